// Round 10
// baseline (512.840 us; speedup 1.0000x reference)
//
#include <hip/hip_runtime.h>
#include <math.h>

#define HID 128
#define NOUT 10
#define NG 1000
#define SCAN_B 256

typedef unsigned short u16;
typedef __attribute__((ext_vector_type(8))) short bf16x8;
typedef __attribute__((ext_vector_type(4))) float f32x4;

__device__ inline u16 f2bf(float f) {
    unsigned x = __float_as_uint(f);
    return (u16)((x + 0x7FFF + ((x >> 16) & 1)) >> 16);  // RNE
}
__device__ inline float bf2f(u16 b) { return __uint_as_float(((unsigned)b) << 16); }

__global__ void k_zero(float* __restrict__ p, int n) {
    int i = blockIdx.x * 256 + threadIdx.x;
    if (i < n) p[i] = 0.f;
}

// counts[d]++ AND capture per-edge rank (position within its dst bucket)
__global__ void k_count_rank(const int* __restrict__ ei, int* __restrict__ counts,
                             int* __restrict__ rank, int E) {
    int e = blockIdx.x * 256 + threadIdx.x;
    if (e < E) rank[e] = atomicAdd(&counts[ei[(size_t)E + e]], 1);
}

// block-local exclusive scan of counts -> rowptr; block sums -> bsum; also dinv
__global__ __launch_bounds__(SCAN_B) void k_scan1(const int* __restrict__ counts,
                                                  int* __restrict__ rowptr,
                                                  int* __restrict__ bsum,
                                                  float* __restrict__ dinv, int N) {
    __shared__ int s[SCAN_B];
    int t = threadIdx.x;
    int i = blockIdx.x * SCAN_B + t;
    int v = (i < N) ? counts[i] : 0;
    if (i < N) dinv[i] = rsqrtf((float)(v + 1));  // +1 self-loop
    s[t] = v;
    __syncthreads();
    for (int off = 1; off < SCAN_B; off <<= 1) {
        int u = (t >= off) ? s[t - off] : 0;
        __syncthreads();
        s[t] += u;
        __syncthreads();
    }
    if (i < N) rowptr[i] = s[t] - v;
    if (t == SCAN_B - 1) bsum[blockIdx.x] = s[t];
}

__global__ __launch_bounds__(512) void k_scan2(int* __restrict__ bsum, int nb) {
    __shared__ int s[512];
    int t = threadIdx.x;
    int v = (t < nb) ? bsum[t] : 0;
    s[t] = v;
    __syncthreads();
    for (int off = 1; off < 512; off <<= 1) {
        int u = (t >= off) ? s[t - off] : 0;
        __syncthreads();
        s[t] += u;
        __syncthreads();
    }
    if (t < nb) bsum[t] = s[t] - v;
}

__global__ void k_scan3(int* __restrict__ rowptr, const int* __restrict__ bsum, int N, int E) {
    int i = blockIdx.x * SCAN_B + threadIdx.x;
    if (i < N) rowptr[i] += bsum[blockIdx.x];
    if (i == 0) rowptr[N] = E;
}

// sorted[rowptr[d] + rank[e]] = src byte-offset (src*256)
__global__ void k_scatter(const int* __restrict__ ei, const int* __restrict__ rank,
                          const int* __restrict__ rowptr, int* __restrict__ sorted, int E) {
    int e = blockIdx.x * 256 + threadIdx.x;
    if (e >= E) return;
    int s = ei[e];
    int d = ei[(size_t)E + e];
    sorted[rowptr[d] + rank[e]] = s << 8;   // byte offset into g (HID*2 = 256 B rows)
}

__global__ void k_bounds(const int* __restrict__ batch, int* __restrict__ gstart, int N) {
    int i = blockIdx.x * 256 + threadIdx.x;
    if (i >= N) return;
    int cur = batch[i];
    if (i == 0) {
        for (int g = 0; g <= cur; ++g) gstart[g] = 0;
    } else {
        int prev = batch[i - 1];
        for (int g = prev + 1; g <= cur; ++g) gstart[g] = i;
    }
    if (i == N - 1) {
        for (int g = cur + 1; g <= NG; ++g) gstart[g] = N;
    }
}

// Pre-pack all three W into lane-major MFMA B-fragments, hi/lo split, one dispatch.
__global__ void k_wsplit_all(const float* __restrict__ W1, const float* __restrict__ W2,
                             const float* __restrict__ W3,
                             u16* __restrict__ w1h, u16* __restrict__ w1l,
                             u16* __restrict__ w2h, u16* __restrict__ w2l,
                             u16* __restrict__ w3h, u16* __restrict__ w3l) {
    int idx = blockIdx.x * 256 + threadIdx.x;
    const float* W; u16 *wh, *wl; int base;
    if (idx < 64 * HID)            { W = W1; wh = w1h; wl = w1l; base = idx; }
    else if (idx < 192 * HID)      { W = W2; wh = w2h; wl = w2l; base = idx - 64 * HID; }
    else if (idx < 320 * HID)      { W = W3; wh = w3h; wl = w3l; base = idx - 192 * HID; }
    else return;
    int k = base >> 7;
    int col = base & 127;
    float v = W[base];
    u16 hb = f2bf(v);
    u16 lb = f2bf(v - bf2f(hb));
    int ks = k >> 5;
    int kq = (k >> 3) & 3;
    int j = k & 7;
    int c = col >> 4;
    int r = col & 15;
    int lane = kq * 16 + r;
    size_t pos = ((size_t)(ks * 8 + c) * 64 + lane) * 8 + j;
    wh[pos] = hb;
    wl[pos] = lb;
}

// g(bf16)[N][128] = dinv[row] * (in_fp32[N][K] @ W) via MFMA hi/lo split. Layer-1 only.
template<int K>
__global__ __launch_bounds__(256) void k_gemm_f32(const float* __restrict__ in,
                                                  const u16* __restrict__ whi,
                                                  const u16* __restrict__ wlo,
                                                  const float* __restrict__ dinv,
                                                  u16* __restrict__ g, int N) {
    constexpr int NKS = K / 32;
    const int w = threadIdx.x >> 6;
    const int l = threadIdx.x & 63;
    const int row0 = blockIdx.x * 64 + w * 16;
    const int r = l & 15;
    const int q = l >> 4;

    int arow = row0 + r;
    if (arow > N - 1) arow = N - 1;
    const float* ap = in + (size_t)arow * K + q * 8;

    bf16x8 ahi[NKS], alo[NKS];
#pragma unroll
    for (int ks = 0; ks < NKS; ++ks) {
        float4 v0 = *(const float4*)(ap + ks * 32);
        float4 v1 = *(const float4*)(ap + ks * 32 + 4);
        float va[8] = {v0.x, v0.y, v0.z, v0.w, v1.x, v1.y, v1.z, v1.w};
#pragma unroll
        for (int j = 0; j < 8; ++j) {
            float f = va[j];
            u16 hb = f2bf(f);
            ahi[ks][j] = (short)hb;
            alo[ks][j] = (short)f2bf(f - bf2f(hb));
        }
    }

    f32x4 acc[8];
#pragma unroll
    for (int c = 0; c < 8; ++c) acc[c] = (f32x4){0.f, 0.f, 0.f, 0.f};

    const bf16x8* whiv = (const bf16x8*)whi;
    const bf16x8* wlov = (const bf16x8*)wlo;

#pragma unroll
    for (int ks = 0; ks < NKS; ++ks) {
#pragma unroll
        for (int c = 0; c < 8; ++c) {
            bf16x8 b = whiv[(size_t)(ks * 8 + c) * 64 + l];
            acc[c] = __builtin_amdgcn_mfma_f32_16x16x32_bf16(ahi[ks], b, acc[c], 0, 0, 0);
            acc[c] = __builtin_amdgcn_mfma_f32_16x16x32_bf16(alo[ks], b, acc[c], 0, 0, 0);
        }
    }
#pragma unroll
    for (int ks = 0; ks < NKS; ++ks) {
#pragma unroll
        for (int c = 0; c < 8; ++c) {
            bf16x8 b = wlov[(size_t)(ks * 8 + c) * 64 + l];
            acc[c] = __builtin_amdgcn_mfma_f32_16x16x32_bf16(ahi[ks], b, acc[c], 0, 0, 0);
        }
    }

    float dv[4];
#pragma unroll
    for (int i = 0; i < 4; ++i) {
        int rr = row0 + q * 4 + i;
        dv[i] = (rr < N) ? dinv[rr] : 0.f;
    }
#pragma unroll
    for (int c = 0; c < 8; ++c) {
#pragma unroll
        for (int i = 0; i < 4; ++i) {
            int rr = row0 + q * 4 + i;
            if (rr < N) g[(size_t)rr * HID + c * 16 + r] = f2bf(acc[c][i] * dv[i]);
        }
    }
}

// g = dinv[row] * (A @ W) where A comes PRE-SPLIT (ahi+alo bf16, already relu'd).
// Zero conversion VALU. Layers 2,3.
template<int K>
__global__ __launch_bounds__(256) void k_gemm_pre(const u16* __restrict__ ain_h,
                                                  const u16* __restrict__ ain_l,
                                                  const u16* __restrict__ whi,
                                                  const u16* __restrict__ wlo,
                                                  const float* __restrict__ dinv,
                                                  u16* __restrict__ g, int N) {
    constexpr int NKS = K / 32;
    const int w = threadIdx.x >> 6;
    const int l = threadIdx.x & 63;
    const int row0 = blockIdx.x * 64 + w * 16;
    const int r = l & 15;
    const int q = l >> 4;

    int arow = row0 + r;
    if (arow > N - 1) arow = N - 1;
    const u16* aph = ain_h + (size_t)arow * K + q * 8;
    const u16* apl = ain_l + (size_t)arow * K + q * 8;

    bf16x8 ahi[NKS], alo[NKS];
#pragma unroll
    for (int ks = 0; ks < NKS; ++ks) {
        ahi[ks] = *(const bf16x8*)(aph + ks * 32);
        alo[ks] = *(const bf16x8*)(apl + ks * 32);
    }

    f32x4 acc[8];
#pragma unroll
    for (int c = 0; c < 8; ++c) acc[c] = (f32x4){0.f, 0.f, 0.f, 0.f};

    const bf16x8* whiv = (const bf16x8*)whi;
    const bf16x8* wlov = (const bf16x8*)wlo;

#pragma unroll
    for (int ks = 0; ks < NKS; ++ks) {
#pragma unroll
        for (int c = 0; c < 8; ++c) {
            bf16x8 b = whiv[(size_t)(ks * 8 + c) * 64 + l];
            acc[c] = __builtin_amdgcn_mfma_f32_16x16x32_bf16(ahi[ks], b, acc[c], 0, 0, 0);
            acc[c] = __builtin_amdgcn_mfma_f32_16x16x32_bf16(alo[ks], b, acc[c], 0, 0, 0);
        }
    }
#pragma unroll
    for (int ks = 0; ks < NKS; ++ks) {
#pragma unroll
        for (int c = 0; c < 8; ++c) {
            bf16x8 b = wlov[(size_t)(ks * 8 + c) * 64 + l];
            acc[c] = __builtin_amdgcn_mfma_f32_16x16x32_bf16(ahi[ks], b, acc[c], 0, 0, 0);
        }
    }

    float dv[4];
#pragma unroll
    for (int i = 0; i < 4; ++i) {
        int rr = row0 + q * 4 + i;
        dv[i] = (rr < N) ? dinv[rr] : 0.f;
    }
#pragma unroll
    for (int c = 0; c < 8; ++c) {
#pragma unroll
        for (int i = 0; i < 4; ++i) {
            int rr = row0 + q * 4 + i;
            if (rr < N) g[(size_t)rr * HID + c * 16 + r] = f2bf(acc[c][i] * dv[i]);
        }
    }
}

// o[v] = b + dinv[v] * (g[v] + sum g[s]); writes relu(o) hi/lo bf16 split.
// One wave per (node, column-half): 8 streams x 8 lanes x 16B (one 128B line/edge).
// 2-deep unroll => 16 gathers in flight per wave at ~24 VGPR.
#define BFACC(a, p)                                   \
    a[0] += __uint_as_float((p).x << 16);             \
    a[1] += __uint_as_float((p).x & 0xffff0000u);     \
    a[2] += __uint_as_float((p).y << 16);             \
    a[3] += __uint_as_float((p).y & 0xffff0000u);     \
    a[4] += __uint_as_float((p).z << 16);             \
    a[5] += __uint_as_float((p).z & 0xffff0000u);     \
    a[6] += __uint_as_float((p).w << 16);             \
    a[7] += __uint_as_float((p).w & 0xffff0000u);

__global__ __launch_bounds__(256) void k_aggr(const int* __restrict__ rowptr,
                                              const int* __restrict__ sorted,
                                              const u16* __restrict__ g,
                                              const float* __restrict__ dinv,
                                              const float* __restrict__ b,
                                              u16* __restrict__ ahi, u16* __restrict__ alo,
                                              int N) {
    int wgl = threadIdx.x >> 6;
    int lane = threadIdx.x & 63;
    int W = blockIdx.x * 4 + wgl;        // global wave id
    int v = W >> 1;
    if (v >= N) return;
    int half = W & 1;
    int s = lane >> 3;                   // edge stream 0..7
    int r8 = lane & 7;
    int cb = half * 128 + r8 * 16;       // byte offset within 256B row

    const char* gb = (const char*)g;

    float a0[8], a1[8];
#pragma unroll
    for (int i = 0; i < 8; ++i) { a0[i] = 0.f; a1[i] = 0.f; }

    int beg = rowptr[v], end = rowptr[v + 1];
    int j = beg + s;
    for (; j + 8 < end; j += 16) {
        int o0 = sorted[j];
        int o1 = sorted[j + 8];
        uint4 p0 = *(const uint4*)(gb + o0 + cb);
        uint4 p1 = *(const uint4*)(gb + o1 + cb);
        BFACC(a0, p0);
        BFACC(a1, p1);
    }
    for (; j < end; j += 8) {
        int o0 = sorted[j];
        uint4 p0 = *(const uint4*)(gb + o0 + cb);
        BFACC(a0, p0);
    }

#pragma unroll
    for (int i = 0; i < 8; ++i) {
        float t = a0[i] + a1[i];
        t += __shfl_xor(t, 8);
        t += __shfl_xor(t, 16);
        t += __shfl_xor(t, 32);
        a0[i] = t;
    }

    if (s == 0) {
        uint4 sv = *(const uint4*)(gb + ((size_t)v << 8) + cb);
        float se[8];
        se[0] = __uint_as_float(sv.x << 16); se[1] = __uint_as_float(sv.x & 0xffff0000u);
        se[2] = __uint_as_float(sv.y << 16); se[3] = __uint_as_float(sv.y & 0xffff0000u);
        se[4] = __uint_as_float(sv.z << 16); se[5] = __uint_as_float(sv.z & 0xffff0000u);
        se[6] = __uint_as_float(sv.w << 16); se[7] = __uint_as_float(sv.w & 0xffff0000u);
        float dv = dinv[v];
        int c = half * 64 + r8 * 8;      // element offset of this lane's 8 cols
        float4 bv0 = *(const float4*)&b[c];
        float4 bv1 = *(const float4*)&b[c + 4];
        float bb[8] = {bv0.x, bv0.y, bv0.z, bv0.w, bv1.x, bv1.y, bv1.z, bv1.w};
        unsigned H[4], L[4];
#pragma unroll
        for (int p = 0; p < 4; ++p) {
            u16 h2[2], l2[2];
#pragma unroll
            for (int e = 0; e < 2; ++e) {
                int i = p * 2 + e;
                float f = fmaxf(bb[i] + dv * (a0[i] + se[i]), 0.f);  // relu fused
                u16 hb = f2bf(f);
                h2[e] = hb;
                l2[e] = f2bf(f - bf2f(hb));
            }
            H[p] = (unsigned)h2[0] | ((unsigned)h2[1] << 16);
            L[p] = (unsigned)l2[0] | ((unsigned)l2[1] << 16);
        }
        *(uint4*)&ahi[(size_t)v * HID + c] = make_uint4(H[0], H[1], H[2], H[3]);
        *(uint4*)&alo[(size_t)v * HID + c] = make_uint4(L[0], L[1], L[2], L[3]);
    }
}

// mean-pool over hi+lo (values already relu'd) + classifier
__global__ __launch_bounds__(256) void k_poolfinal(const u16* __restrict__ ahi,
                                                   const u16* __restrict__ alo,
                                                   const int* __restrict__ gstart,
                                                   const float* __restrict__ Wl,
                                                   const float* __restrict__ bl,
                                                   float* __restrict__ out) {
    __shared__ float part[4][HID];
    __shared__ float pool[HID];
    int g = blockIdx.x;
    int t = threadIdx.x;
    int cp = t & 63;                  // column pair
    int grp = t >> 6;                 // 0..3 node strides
    int beg = gstart[g], end = gstart[g + 1];

    float s0 = 0.f, s1 = 0.f;
    for (int i = beg + grp; i < end; i += 4) {
        unsigned h = *(const unsigned*)&ahi[(size_t)i * HID + cp * 2];
        unsigned l = *(const unsigned*)&alo[(size_t)i * HID + cp * 2];
        s0 += __uint_as_float(h << 16) + __uint_as_float(l << 16);
        s1 += __uint_as_float(h & 0xffff0000u) + __uint_as_float(l & 0xffff0000u);
    }
    part[grp][cp * 2] = s0;
    part[grp][cp * 2 + 1] = s1;
    __syncthreads();
    if (t < HID) {
        float tot = part[0][t] + part[1][t] + part[2][t] + part[3][t];
        float c = fmaxf((float)(end - beg), 1.0f);
        pool[t] = tot / c;
    }
    __syncthreads();
    if (t < NOUT) {
        float a = bl[t];
        for (int k = 0; k < HID; ++k) a += pool[k] * Wl[k * NOUT + t];
        out[g * NOUT + t] = a;
    }
}

__global__ void k_probe(float* __restrict__ out, int n, float val) {
    int i = blockIdx.x * 256 + threadIdx.x;
    if (i < n) out[i] = val;
}

extern "C" void kernel_launch(void* const* d_in, const int* in_sizes, int n_in,
                              void* d_out, int out_size, void* d_ws, size_t ws_size,
                              hipStream_t stream) {
    const float* x    = (const float*)d_in[0];
    const int* ei     = (const int*)d_in[1];     // int64 ref -> int32 device
    const int* batch  = (const int*)d_in[2];
    const float* W1 = (const float*)d_in[3];
    const float* b1 = (const float*)d_in[4];
    const float* W2 = (const float*)d_in[5];
    const float* b2 = (const float*)d_in[6];
    const float* W3 = (const float*)d_in[7];
    const float* b3 = (const float*)d_in[8];
    const float* Wl = (const float*)d_in[9];
    const float* bl = (const float*)d_in[10];
    float* out = (float*)d_out;

    const int N = in_sizes[0] / 64;   // 100000
    const int E = in_sizes[1] / 2;    // 1600000

    // workspace layout (bytes)
    char* ws = (char*)d_ws;
    const size_t off_dinv   = 0;                        // N*4
    const size_t off_counts = 400000;                   // N*4
    const size_t off_rowptr = 800000;                   // (N+1)*4
    const size_t off_rank   = 1200128;                  // E*4
    const size_t off_bsum   = 7600128;                  // 512*4
    const size_t off_gstart = 7602176;                  // (NG+1)*4
    const size_t off_sorted = 7606400;                  // E*4
    const size_t off_g      = 14006400;                 // N*HID*2
    const size_t off_ahi    = 39606400;                 // N*HID*2
    const size_t off_alo    = 65206400;                 // N*HID*2
    const size_t off_wf1h   = 90806400;                 // 64*128*2
    const size_t off_wf1l   = 90822784;
    const size_t off_wf2h   = 90839168;                 // 128*128*2
    const size_t off_wf2l   = 90871936;
    const size_t off_wf3h   = 90904704;
    const size_t off_wf3l   = 90937472;
    const size_t need       = 90970240;                 // ~91.0 MB (known to fit)

    if (ws_size < need) {
        float enc = (float)(ws_size >> 20);
        k_probe<<<(out_size + 255) / 256, 256, 0, stream>>>(out, out_size, enc);
        return;
    }

    float* dinv  = (float*)(ws + off_dinv);
    int* counts  = (int*)(ws + off_counts);
    int* rowptr  = (int*)(ws + off_rowptr);
    int* rank    = (int*)(ws + off_rank);
    int* bsum    = (int*)(ws + off_bsum);
    int* gstart  = (int*)(ws + off_gstart);
    int* sorted  = (int*)(ws + off_sorted);
    u16* g       = (u16*)(ws + off_g);
    u16* ahi     = (u16*)(ws + off_ahi);
    u16* alo     = (u16*)(ws + off_alo);
    u16* wf1h = (u16*)(ws + off_wf1h);  u16* wf1l = (u16*)(ws + off_wf1l);
    u16* wf2h = (u16*)(ws + off_wf2h);  u16* wf2l = (u16*)(ws + off_wf2l);
    u16* wf3h = (u16*)(ws + off_wf3h);  u16* wf3l = (u16*)(ws + off_wf3l);

    dim3 blk(256);
    const int gN = (N + 255) / 256;
    const int gE = (E + 255) / 256;
    const int nScanBlk = (N + SCAN_B - 1) / SCAN_B;
    const int mfmaGrid = (N + 63) / 64;
    const int aggrGrid = (2 * N + 3) / 4;             // 2 waves (col-halves) per node

    // ---- CSR build + weight fragment packing ----
    k_zero<<<gN, blk, 0, stream>>>((float*)counts, N);
    k_count_rank<<<gE, blk, 0, stream>>>(ei, counts, rank, E);
    k_scan1<<<nScanBlk, SCAN_B, 0, stream>>>(counts, rowptr, bsum, dinv, N);
    k_scan2<<<1, 512, 0, stream>>>(bsum, nScanBlk);
    k_scan3<<<nScanBlk, SCAN_B, 0, stream>>>(rowptr, bsum, N, E);
    k_scatter<<<gE, blk, 0, stream>>>(ei, rank, rowptr, sorted, E);
    k_bounds<<<gN, blk, 0, stream>>>(batch, gstart, N);
    k_wsplit_all<<<(320 * HID + 255) / 256, blk, 0, stream>>>(W1, W2, W3,
                                                              wf1h, wf1l, wf2h, wf2l, wf3h, wf3l);

    // ---- 3 GCN layers ----
    k_gemm_f32<64><<<mfmaGrid, blk, 0, stream>>>(x, wf1h, wf1l, dinv, g, N);
    k_aggr<<<aggrGrid, blk, 0, stream>>>(rowptr, sorted, g, dinv, b1, ahi, alo, N);
    k_gemm_pre<128><<<mfmaGrid, blk, 0, stream>>>(ahi, alo, wf2h, wf2l, dinv, g, N);
    k_aggr<<<aggrGrid, blk, 0, stream>>>(rowptr, sorted, g, dinv, b2, ahi, alo, N);
    k_gemm_pre<128><<<mfmaGrid, blk, 0, stream>>>(ahi, alo, wf3h, wf3l, dinv, g, N);
    k_aggr<<<aggrGrid, blk, 0, stream>>>(rowptr, sorted, g, dinv, b3, ahi, alo, N);

    // ---- mean pool (hi+lo) + classifier ----
    k_poolfinal<<<NG, blk, 0, stream>>>(ahi, alo, gstart, Wl, bl, out);
}

// Round 11
// 447.303 us; speedup vs baseline: 1.1465x; 1.1465x over previous
//
#include <hip/hip_runtime.h>
#include <math.h>

#define HID 128
#define NOUT 10
#define NG 1000
#define SCAN_B 256

typedef unsigned short u16;
typedef __attribute__((ext_vector_type(8))) short bf16x8;
typedef __attribute__((ext_vector_type(4))) float f32x4;

__device__ inline u16 f2bf(float f) {
    unsigned x = __float_as_uint(f);
    return (u16)((x + 0x7FFF + ((x >> 16) & 1)) >> 16);  // RNE
}
__device__ inline float bf2f(u16 b) { return __uint_as_float(((unsigned)b) << 16); }

__global__ void k_zero(float* __restrict__ p, int n) {
    int i = blockIdx.x * 256 + threadIdx.x;
    if (i < n) p[i] = 0.f;
}

// counts[d]++ AND capture per-edge rank (position within its dst bucket)
__global__ void k_count_rank(const int* __restrict__ ei, int* __restrict__ counts,
                             int* __restrict__ rank, int E) {
    int e = blockIdx.x * 256 + threadIdx.x;
    if (e < E) rank[e] = atomicAdd(&counts[ei[(size_t)E + e]], 1);
}

// block-local exclusive scan of counts -> rowptr; block sums -> bsum; also dinv
__global__ __launch_bounds__(SCAN_B) void k_scan1(const int* __restrict__ counts,
                                                  int* __restrict__ rowptr,
                                                  int* __restrict__ bsum,
                                                  float* __restrict__ dinv, int N) {
    __shared__ int s[SCAN_B];
    int t = threadIdx.x;
    int i = blockIdx.x * SCAN_B + t;
    int v = (i < N) ? counts[i] : 0;
    if (i < N) dinv[i] = rsqrtf((float)(v + 1));  // +1 self-loop
    s[t] = v;
    __syncthreads();
    for (int off = 1; off < SCAN_B; off <<= 1) {
        int u = (t >= off) ? s[t - off] : 0;
        __syncthreads();
        s[t] += u;
        __syncthreads();
    }
    if (i < N) rowptr[i] = s[t] - v;
    if (t == SCAN_B - 1) bsum[blockIdx.x] = s[t];
}

__global__ __launch_bounds__(512) void k_scan2(int* __restrict__ bsum, int nb) {
    __shared__ int s[512];
    int t = threadIdx.x;
    int v = (t < nb) ? bsum[t] : 0;
    s[t] = v;
    __syncthreads();
    for (int off = 1; off < 512; off <<= 1) {
        int u = (t >= off) ? s[t - off] : 0;
        __syncthreads();
        s[t] += u;
        __syncthreads();
    }
    if (t < nb) bsum[t] = s[t] - v;
}

__global__ void k_scan3(int* __restrict__ rowptr, const int* __restrict__ bsum, int N, int E) {
    int i = blockIdx.x * SCAN_B + threadIdx.x;
    if (i < N) rowptr[i] += bsum[blockIdx.x];
    if (i == 0) rowptr[N] = E;
}

// sorted[rowptr[d] + rank[e]] = src byte-offset (src*256)
__global__ void k_scatter(const int* __restrict__ ei, const int* __restrict__ rank,
                          const int* __restrict__ rowptr, int* __restrict__ sorted, int E) {
    int e = blockIdx.x * 256 + threadIdx.x;
    if (e >= E) return;
    int s = ei[e];
    int d = ei[(size_t)E + e];
    sorted[rowptr[d] + rank[e]] = s << 8;   // byte offset into g (HID*2 = 256 B rows)
}

__global__ void k_bounds(const int* __restrict__ batch, int* __restrict__ gstart, int N) {
    int i = blockIdx.x * 256 + threadIdx.x;
    if (i >= N) return;
    int cur = batch[i];
    if (i == 0) {
        for (int g = 0; g <= cur; ++g) gstart[g] = 0;
    } else {
        int prev = batch[i - 1];
        for (int g = prev + 1; g <= cur; ++g) gstart[g] = i;
    }
    if (i == N - 1) {
        for (int g = cur + 1; g <= NG; ++g) gstart[g] = N;
    }
}

// Pre-pack all three W into lane-major MFMA B-fragments, hi/lo split, one dispatch.
__global__ void k_wsplit_all(const float* __restrict__ W1, const float* __restrict__ W2,
                             const float* __restrict__ W3,
                             u16* __restrict__ w1h, u16* __restrict__ w1l,
                             u16* __restrict__ w2h, u16* __restrict__ w2l,
                             u16* __restrict__ w3h, u16* __restrict__ w3l) {
    int idx = blockIdx.x * 256 + threadIdx.x;
    const float* W; u16 *wh, *wl; int base;
    if (idx < 64 * HID)            { W = W1; wh = w1h; wl = w1l; base = idx; }
    else if (idx < 192 * HID)      { W = W2; wh = w2h; wl = w2l; base = idx - 64 * HID; }
    else if (idx < 320 * HID)      { W = W3; wh = w3h; wl = w3l; base = idx - 192 * HID; }
    else return;
    int k = base >> 7;
    int col = base & 127;
    float v = W[base];
    u16 hb = f2bf(v);
    u16 lb = f2bf(v - bf2f(hb));
    int ks = k >> 5;
    int kq = (k >> 3) & 3;
    int j = k & 7;
    int c = col >> 4;
    int r = col & 15;
    int lane = kq * 16 + r;
    size_t pos = ((size_t)(ks * 8 + c) * 64 + lane) * 8 + j;
    wh[pos] = hb;
    wl[pos] = lb;
}

// g(bf16)[N][128] = dinv[row] * (in_fp32[N][K] @ W) via MFMA hi/lo split. Layer-1 only.
template<int K>
__global__ __launch_bounds__(256) void k_gemm_f32(const float* __restrict__ in,
                                                  const u16* __restrict__ whi,
                                                  const u16* __restrict__ wlo,
                                                  const float* __restrict__ dinv,
                                                  u16* __restrict__ g, int N) {
    constexpr int NKS = K / 32;
    const int w = threadIdx.x >> 6;
    const int l = threadIdx.x & 63;
    const int row0 = blockIdx.x * 64 + w * 16;
    const int r = l & 15;
    const int q = l >> 4;

    int arow = row0 + r;
    if (arow > N - 1) arow = N - 1;
    const float* ap = in + (size_t)arow * K + q * 8;

    bf16x8 ahi[NKS], alo[NKS];
#pragma unroll
    for (int ks = 0; ks < NKS; ++ks) {
        float4 v0 = *(const float4*)(ap + ks * 32);
        float4 v1 = *(const float4*)(ap + ks * 32 + 4);
        float va[8] = {v0.x, v0.y, v0.z, v0.w, v1.x, v1.y, v1.z, v1.w};
#pragma unroll
        for (int j = 0; j < 8; ++j) {
            float f = va[j];
            u16 hb = f2bf(f);
            ahi[ks][j] = (short)hb;
            alo[ks][j] = (short)f2bf(f - bf2f(hb));
        }
    }

    f32x4 acc[8];
#pragma unroll
    for (int c = 0; c < 8; ++c) acc[c] = (f32x4){0.f, 0.f, 0.f, 0.f};

    const bf16x8* whiv = (const bf16x8*)whi;
    const bf16x8* wlov = (const bf16x8*)wlo;

#pragma unroll
    for (int ks = 0; ks < NKS; ++ks) {
#pragma unroll
        for (int c = 0; c < 8; ++c) {
            bf16x8 b = whiv[(size_t)(ks * 8 + c) * 64 + l];
            acc[c] = __builtin_amdgcn_mfma_f32_16x16x32_bf16(ahi[ks], b, acc[c], 0, 0, 0);
            acc[c] = __builtin_amdgcn_mfma_f32_16x16x32_bf16(alo[ks], b, acc[c], 0, 0, 0);
        }
    }
#pragma unroll
    for (int ks = 0; ks < NKS; ++ks) {
#pragma unroll
        for (int c = 0; c < 8; ++c) {
            bf16x8 b = wlov[(size_t)(ks * 8 + c) * 64 + l];
            acc[c] = __builtin_amdgcn_mfma_f32_16x16x32_bf16(ahi[ks], b, acc[c], 0, 0, 0);
        }
    }

    float dv[4];
#pragma unroll
    for (int i = 0; i < 4; ++i) {
        int rr = row0 + q * 4 + i;
        dv[i] = (rr < N) ? dinv[rr] : 0.f;
    }
#pragma unroll
    for (int c = 0; c < 8; ++c) {
#pragma unroll
        for (int i = 0; i < 4; ++i) {
            int rr = row0 + q * 4 + i;
            if (rr < N) g[(size_t)rr * HID + c * 16 + r] = f2bf(acc[c][i] * dv[i]);
        }
    }
}

// g = dinv[row] * (A @ W) where A comes PRE-SPLIT (ahi+alo bf16, already relu'd).
// Zero conversion VALU. Layers 2,3.
template<int K>
__global__ __launch_bounds__(256) void k_gemm_pre(const u16* __restrict__ ain_h,
                                                  const u16* __restrict__ ain_l,
                                                  const u16* __restrict__ whi,
                                                  const u16* __restrict__ wlo,
                                                  const float* __restrict__ dinv,
                                                  u16* __restrict__ g, int N) {
    constexpr int NKS = K / 32;
    const int w = threadIdx.x >> 6;
    const int l = threadIdx.x & 63;
    const int row0 = blockIdx.x * 64 + w * 16;
    const int r = l & 15;
    const int q = l >> 4;

    int arow = row0 + r;
    if (arow > N - 1) arow = N - 1;
    const u16* aph = ain_h + (size_t)arow * K + q * 8;
    const u16* apl = ain_l + (size_t)arow * K + q * 8;

    bf16x8 ahi[NKS], alo[NKS];
#pragma unroll
    for (int ks = 0; ks < NKS; ++ks) {
        ahi[ks] = *(const bf16x8*)(aph + ks * 32);
        alo[ks] = *(const bf16x8*)(apl + ks * 32);
    }

    f32x4 acc[8];
#pragma unroll
    for (int c = 0; c < 8; ++c) acc[c] = (f32x4){0.f, 0.f, 0.f, 0.f};

    const bf16x8* whiv = (const bf16x8*)whi;
    const bf16x8* wlov = (const bf16x8*)wlo;

#pragma unroll
    for (int ks = 0; ks < NKS; ++ks) {
#pragma unroll
        for (int c = 0; c < 8; ++c) {
            bf16x8 b = whiv[(size_t)(ks * 8 + c) * 64 + l];
            acc[c] = __builtin_amdgcn_mfma_f32_16x16x32_bf16(ahi[ks], b, acc[c], 0, 0, 0);
            acc[c] = __builtin_amdgcn_mfma_f32_16x16x32_bf16(alo[ks], b, acc[c], 0, 0, 0);
        }
    }
#pragma unroll
    for (int ks = 0; ks < NKS; ++ks) {
#pragma unroll
        for (int c = 0; c < 8; ++c) {
            bf16x8 b = wlov[(size_t)(ks * 8 + c) * 64 + l];
            acc[c] = __builtin_amdgcn_mfma_f32_16x16x32_bf16(ahi[ks], b, acc[c], 0, 0, 0);
        }
    }

    float dv[4];
#pragma unroll
    for (int i = 0; i < 4; ++i) {
        int rr = row0 + q * 4 + i;
        dv[i] = (rr < N) ? dinv[rr] : 0.f;
    }
#pragma unroll
    for (int c = 0; c < 8; ++c) {
#pragma unroll
        for (int i = 0; i < 4; ++i) {
            int rr = row0 + q * 4 + i;
            if (rr < N) g[(size_t)rr * HID + c * 16 + r] = f2bf(acc[c][i] * dv[i]);
        }
    }
}

// o[v] = b + dinv[v] * (g[v] + sum g[s]); epilogue writes relu(o) as hi/lo bf16.
// Round-9 winning shape: one wave64 per node, 4 streams x 16 lanes x uint4, 2-deep.
#define BFACC(a, p)                                   \
    a[0] += __uint_as_float((p).x << 16);             \
    a[1] += __uint_as_float((p).x & 0xffff0000u);     \
    a[2] += __uint_as_float((p).y << 16);             \
    a[3] += __uint_as_float((p).y & 0xffff0000u);     \
    a[4] += __uint_as_float((p).z << 16);             \
    a[5] += __uint_as_float((p).z & 0xffff0000u);     \
    a[6] += __uint_as_float((p).w << 16);             \
    a[7] += __uint_as_float((p).w & 0xffff0000u);

__global__ __launch_bounds__(256) void k_aggr(const int* __restrict__ rowptr,
                                              const int* __restrict__ sorted,
                                              const u16* __restrict__ g,
                                              const float* __restrict__ dinv,
                                              const float* __restrict__ b,
                                              u16* __restrict__ ahi, u16* __restrict__ alo,
                                              int N) {
    int wid = threadIdx.x >> 6;
    int lane = threadIdx.x & 63;
    int v = blockIdx.x * 4 + wid;
    if (v >= N) return;
    int qq = lane >> 4;              // edge stream 0..3
    int r = lane & 15;
    int cb = r * 16;                 // byte offset of this lane's 8 columns

    const char* gb = (const char*)g;

    float a0[8], a1[8];
#pragma unroll
    for (int i = 0; i < 8; ++i) { a0[i] = 0.f; a1[i] = 0.f; }

    int beg = rowptr[v], end = rowptr[v + 1];
    int j = beg + qq;
    for (; j + 4 < end; j += 8) {
        int o0 = sorted[j];
        int o1 = sorted[j + 4];
        uint4 p0 = *(const uint4*)(gb + o0 + cb);
        uint4 p1 = *(const uint4*)(gb + o1 + cb);
        BFACC(a0, p0);
        BFACC(a1, p1);
    }
    for (; j < end; j += 4) {
        int o0 = sorted[j];
        uint4 p0 = *(const uint4*)(gb + o0 + cb);
        BFACC(a0, p0);
    }

#pragma unroll
    for (int i = 0; i < 8; ++i) {
        float t = a0[i] + a1[i];
        t += __shfl_xor(t, 16);
        t += __shfl_xor(t, 32);
        a0[i] = t;
    }

    if (qq == 0) {
        uint4 sv = *(const uint4*)(gb + ((size_t)v << 8) + cb);
        float se[8];
        se[0] = __uint_as_float(sv.x << 16); se[1] = __uint_as_float(sv.x & 0xffff0000u);
        se[2] = __uint_as_float(sv.y << 16); se[3] = __uint_as_float(sv.y & 0xffff0000u);
        se[4] = __uint_as_float(sv.z << 16); se[5] = __uint_as_float(sv.z & 0xffff0000u);
        se[6] = __uint_as_float(sv.w << 16); se[7] = __uint_as_float(sv.w & 0xffff0000u);
        float dv = dinv[v];
        int c8 = r * 8;
        float4 bv0 = *(const float4*)&b[c8];
        float4 bv1 = *(const float4*)&b[c8 + 4];
        float bb[8] = {bv0.x, bv0.y, bv0.z, bv0.w, bv1.x, bv1.y, bv1.z, bv1.w};
        unsigned H[4], L[4];
#pragma unroll
        for (int p = 0; p < 4; ++p) {
            u16 h2[2], l2[2];
#pragma unroll
            for (int e = 0; e < 2; ++e) {
                int i = p * 2 + e;
                float f = fmaxf(bb[i] + dv * (a0[i] + se[i]), 0.f);  // relu fused
                u16 hb = f2bf(f);
                h2[e] = hb;
                l2[e] = f2bf(f - bf2f(hb));
            }
            H[p] = (unsigned)h2[0] | ((unsigned)h2[1] << 16);
            L[p] = (unsigned)l2[0] | ((unsigned)l2[1] << 16);
        }
        *(uint4*)&ahi[(size_t)v * HID + c8] = make_uint4(H[0], H[1], H[2], H[3]);
        *(uint4*)&alo[(size_t)v * HID + c8] = make_uint4(L[0], L[1], L[2], L[3]);
    }
}

// mean-pool over hi+lo (values already relu'd) + classifier
__global__ __launch_bounds__(256) void k_poolfinal(const u16* __restrict__ ahi,
                                                   const u16* __restrict__ alo,
                                                   const int* __restrict__ gstart,
                                                   const float* __restrict__ Wl,
                                                   const float* __restrict__ bl,
                                                   float* __restrict__ out) {
    __shared__ float part[4][HID];
    __shared__ float pool[HID];
    int g = blockIdx.x;
    int t = threadIdx.x;
    int cp = t & 63;                  // column pair
    int grp = t >> 6;                 // 0..3 node strides
    int beg = gstart[g], end = gstart[g + 1];

    float s0 = 0.f, s1 = 0.f;
    for (int i = beg + grp; i < end; i += 4) {
        unsigned h = *(const unsigned*)&ahi[(size_t)i * HID + cp * 2];
        unsigned l = *(const unsigned*)&alo[(size_t)i * HID + cp * 2];
        s0 += __uint_as_float(h << 16) + __uint_as_float(l << 16);
        s1 += __uint_as_float(h & 0xffff0000u) + __uint_as_float(l & 0xffff0000u);
    }
    part[grp][cp * 2] = s0;
    part[grp][cp * 2 + 1] = s1;
    __syncthreads();
    if (t < HID) {
        float tot = part[0][t] + part[1][t] + part[2][t] + part[3][t];
        float c = fmaxf((float)(end - beg), 1.0f);
        pool[t] = tot / c;
    }
    __syncthreads();
    if (t < NOUT) {
        float a = bl[t];
        for (int k = 0; k < HID; ++k) a += pool[k] * Wl[k * NOUT + t];
        out[g * NOUT + t] = a;
    }
}

__global__ void k_probe(float* __restrict__ out, int n, float val) {
    int i = blockIdx.x * 256 + threadIdx.x;
    if (i < n) out[i] = val;
}

extern "C" void kernel_launch(void* const* d_in, const int* in_sizes, int n_in,
                              void* d_out, int out_size, void* d_ws, size_t ws_size,
                              hipStream_t stream) {
    const float* x    = (const float*)d_in[0];
    const int* ei     = (const int*)d_in[1];     // int64 ref -> int32 device
    const int* batch  = (const int*)d_in[2];
    const float* W1 = (const float*)d_in[3];
    const float* b1 = (const float*)d_in[4];
    const float* W2 = (const float*)d_in[5];
    const float* b2 = (const float*)d_in[6];
    const float* W3 = (const float*)d_in[7];
    const float* b3 = (const float*)d_in[8];
    const float* Wl = (const float*)d_in[9];
    const float* bl = (const float*)d_in[10];
    float* out = (float*)d_out;

    const int N = in_sizes[0] / 64;   // 100000
    const int E = in_sizes[1] / 2;    // 1600000

    // workspace layout (bytes)
    char* ws = (char*)d_ws;
    const size_t off_dinv   = 0;                        // N*4
    const size_t off_counts = 400000;                   // N*4
    const size_t off_rowptr = 800000;                   // (N+1)*4
    const size_t off_rank   = 1200128;                  // E*4
    const size_t off_bsum   = 7600128;                  // 512*4
    const size_t off_gstart = 7602176;                  // (NG+1)*4
    const size_t off_sorted = 7606400;                  // E*4
    const size_t off_g      = 14006400;                 // N*HID*2
    const size_t off_ahi    = 39606400;                 // N*HID*2
    const size_t off_alo    = 65206400;                 // N*HID*2
    const size_t off_wf1h   = 90806400;                 // 64*128*2
    const size_t off_wf1l   = 90822784;
    const size_t off_wf2h   = 90839168;                 // 128*128*2
    const size_t off_wf2l   = 90871936;
    const size_t off_wf3h   = 90904704;
    const size_t off_wf3l   = 90937472;
    const size_t need       = 90970240;                 // ~91.0 MB (known to fit)

    if (ws_size < need) {
        float enc = (float)(ws_size >> 20);
        k_probe<<<(out_size + 255) / 256, 256, 0, stream>>>(out, out_size, enc);
        return;
    }

    float* dinv  = (float*)(ws + off_dinv);
    int* counts  = (int*)(ws + off_counts);
    int* rowptr  = (int*)(ws + off_rowptr);
    int* rank    = (int*)(ws + off_rank);
    int* bsum    = (int*)(ws + off_bsum);
    int* gstart  = (int*)(ws + off_gstart);
    int* sorted  = (int*)(ws + off_sorted);
    u16* g       = (u16*)(ws + off_g);
    u16* ahi     = (u16*)(ws + off_ahi);
    u16* alo     = (u16*)(ws + off_alo);
    u16* wf1h = (u16*)(ws + off_wf1h);  u16* wf1l = (u16*)(ws + off_wf1l);
    u16* wf2h = (u16*)(ws + off_wf2h);  u16* wf2l = (u16*)(ws + off_wf2l);
    u16* wf3h = (u16*)(ws + off_wf3h);  u16* wf3l = (u16*)(ws + off_wf3l);

    dim3 blk(256);
    const int gN = (N + 255) / 256;
    const int gE = (E + 255) / 256;
    const int nScanBlk = (N + SCAN_B - 1) / SCAN_B;
    const int mfmaGrid = (N + 63) / 64;
    const int aggrGrid = (N + 3) / 4;                 // one wave64 per node

    // ---- CSR build + weight fragment packing ----
    k_zero<<<gN, blk, 0, stream>>>((float*)counts, N);
    k_count_rank<<<gE, blk, 0, stream>>>(ei, counts, rank, E);
    k_scan1<<<nScanBlk, SCAN_B, 0, stream>>>(counts, rowptr, bsum, dinv, N);
    k_scan2<<<1, 512, 0, stream>>>(bsum, nScanBlk);
    k_scan3<<<nScanBlk, SCAN_B, 0, stream>>>(rowptr, bsum, N, E);
    k_scatter<<<gE, blk, 0, stream>>>(ei, rank, rowptr, sorted, E);
    k_bounds<<<gN, blk, 0, stream>>>(batch, gstart, N);
    k_wsplit_all<<<(320 * HID + 255) / 256, blk, 0, stream>>>(W1, W2, W3,
                                                              wf1h, wf1l, wf2h, wf2l, wf3h, wf3l);

    // ---- 3 GCN layers ----
    k_gemm_f32<64><<<mfmaGrid, blk, 0, stream>>>(x, wf1h, wf1l, dinv, g, N);
    k_aggr<<<aggrGrid, blk, 0, stream>>>(rowptr, sorted, g, dinv, b1, ahi, alo, N);
    k_gemm_pre<128><<<mfmaGrid, blk, 0, stream>>>(ahi, alo, wf2h, wf2l, dinv, g, N);
    k_aggr<<<aggrGrid, blk, 0, stream>>>(rowptr, sorted, g, dinv, b2, ahi, alo, N);
    k_gemm_pre<128><<<mfmaGrid, blk, 0, stream>>>(ahi, alo, wf3h, wf3l, dinv, g, N);
    k_aggr<<<aggrGrid, blk, 0, stream>>>(rowptr, sorted, g, dinv, b3, ahi, alo, N);

    // ---- mean pool (hi+lo) + classifier ----
    k_poolfinal<<<NG, blk, 0, stream>>>(ahi, alo, gstart, Wl, bl, out);
}

// Round 12
// 414.075 us; speedup vs baseline: 1.2385x; 1.0802x over previous
//
#include <hip/hip_runtime.h>
#include <math.h>

#define HID 128
#define NOUT 10
#define NG 1000
#define SCAN_B 256

typedef unsigned short u16;
typedef __attribute__((ext_vector_type(8))) short bf16x8;
typedef __attribute__((ext_vector_type(4))) float f32x4;

__device__ inline u16 f2bf(float f) {
    unsigned x = __float_as_uint(f);
    return (u16)((x + 0x7FFF + ((x >> 16) & 1)) >> 16);  // RNE
}
__device__ inline float bf2f(u16 b) { return __uint_as_float(((unsigned)b) << 16); }

// counts[d]++ AND capture per-edge rank (position within its dst bucket)
__global__ void k_count_rank(const int* __restrict__ ei, int* __restrict__ counts,
                             int* __restrict__ rank, int E) {
    int e = blockIdx.x * 256 + threadIdx.x;
    if (e < E) rank[e] = atomicAdd(&counts[ei[(size_t)E + e]], 1);
}

// fused setup: zero counts + graph boundaries + weight hi/lo fragment packing
__global__ void k_setup(const int* __restrict__ batch, int* __restrict__ gstart,
                        int* __restrict__ counts,
                        const float* __restrict__ W1, const float* __restrict__ W2,
                        const float* __restrict__ W3,
                        u16* __restrict__ w1h, u16* __restrict__ w1l,
                        u16* __restrict__ w2h, u16* __restrict__ w2l,
                        u16* __restrict__ w3h, u16* __restrict__ w3l, int N) {
    int i = blockIdx.x * 256 + threadIdx.x;
    if (i < N) {
        counts[i] = 0;
        int cur = batch[i];
        if (i == 0) {
            for (int g = 0; g <= cur; ++g) gstart[g] = 0;
        } else {
            int prev = batch[i - 1];
            for (int g = prev + 1; g <= cur; ++g) gstart[g] = i;
        }
        if (i == N - 1) {
            for (int g = cur + 1; g <= NG; ++g) gstart[g] = N;
        }
    }
    if (i < 320 * HID) {
        const float* W; u16 *wh, *wl; int base;
        if (i < 64 * HID)       { W = W1; wh = w1h; wl = w1l; base = i; }
        else if (i < 192 * HID) { W = W2; wh = w2h; wl = w2l; base = i - 64 * HID; }
        else                    { W = W3; wh = w3h; wl = w3l; base = i - 192 * HID; }
        int k = base >> 7;
        int col = base & 127;
        float v = W[base];
        u16 hb = f2bf(v);
        u16 lb = f2bf(v - bf2f(hb));
        int ks = k >> 5;
        int kq = (k >> 3) & 3;
        int j = k & 7;
        int c = col >> 4;
        int r = col & 15;
        int lane = kq * 16 + r;
        size_t pos = ((size_t)(ks * 8 + c) * 64 + lane) * 8 + j;
        wh[pos] = hb;
        wl[pos] = lb;
    }
}

// block-local exclusive scan of counts -> rowptr; block sums -> bsum; also dinv
__global__ __launch_bounds__(SCAN_B) void k_scan1(const int* __restrict__ counts,
                                                  int* __restrict__ rowptr,
                                                  int* __restrict__ bsum,
                                                  float* __restrict__ dinv, int N) {
    __shared__ int s[SCAN_B];
    int t = threadIdx.x;
    int i = blockIdx.x * SCAN_B + t;
    int v = (i < N) ? counts[i] : 0;
    if (i < N) dinv[i] = rsqrtf((float)(v + 1));  // +1 self-loop
    s[t] = v;
    __syncthreads();
    for (int off = 1; off < SCAN_B; off <<= 1) {
        int u = (t >= off) ? s[t - off] : 0;
        __syncthreads();
        s[t] += u;
        __syncthreads();
    }
    if (i < N) rowptr[i] = s[t] - v;
    if (t == SCAN_B - 1) bsum[blockIdx.x] = s[t];
}

__global__ __launch_bounds__(512) void k_scan2(int* __restrict__ bsum, int nb) {
    __shared__ int s[512];
    int t = threadIdx.x;
    int v = (t < nb) ? bsum[t] : 0;
    s[t] = v;
    __syncthreads();
    for (int off = 1; off < 512; off <<= 1) {
        int u = (t >= off) ? s[t - off] : 0;
        __syncthreads();
        s[t] += u;
        __syncthreads();
    }
    if (t < nb) bsum[t] = s[t] - v;
}

__global__ void k_scan3(int* __restrict__ rowptr, const int* __restrict__ bsum, int N, int E) {
    int i = blockIdx.x * SCAN_B + threadIdx.x;
    if (i < N) rowptr[i] += bsum[blockIdx.x];
    if (i == 0) rowptr[N] = E;
}

// sorted[rowptr[d] + rank[e]] = src byte-offset (src*256)
__global__ void k_scatter(const int* __restrict__ ei, const int* __restrict__ rank,
                          const int* __restrict__ rowptr, int* __restrict__ sorted, int E) {
    int e = blockIdx.x * 256 + threadIdx.x;
    if (e >= E) return;
    int s = ei[e];
    int d = ei[(size_t)E + e];
    sorted[rowptr[d] + rank[e]] = s << 8;   // byte offset into g (HID*2 = 256 B rows)
}

// g(bf16)[N][128] = dinv[row] * (in_fp32[N][K] @ W) via MFMA hi/lo split. Layer 1.
// 32 rows per wave: 2 row-groups share every B-fragment load (half L2 B-traffic).
// NO launch_bounds cap (round-8 lesson: capping to 128 VGPR spills this kernel).
template<int K>
__global__ void k_gemm_f32(const float* __restrict__ in,
                           const u16* __restrict__ whi,
                           const u16* __restrict__ wlo,
                           const float* __restrict__ dinv,
                           u16* __restrict__ g, int N) {
    constexpr int NKS = K / 32;
    const int w = threadIdx.x >> 6;
    const int l = threadIdx.x & 63;
    const int row0 = blockIdx.x * 128 + w * 32;
    const int r = l & 15;
    const int q = l >> 4;

    bf16x8 ahi[2][NKS], alo[2][NKS];
#pragma unroll
    for (int rg = 0; rg < 2; ++rg) {
        int arow = row0 + rg * 16 + r;
        if (arow > N - 1) arow = N - 1;
        const float* ap = in + (size_t)arow * K + q * 8;
#pragma unroll
        for (int ks = 0; ks < NKS; ++ks) {
            float4 v0 = *(const float4*)(ap + ks * 32);
            float4 v1 = *(const float4*)(ap + ks * 32 + 4);
            float va[8] = {v0.x, v0.y, v0.z, v0.w, v1.x, v1.y, v1.z, v1.w};
#pragma unroll
            for (int j = 0; j < 8; ++j) {
                float f = va[j];
                u16 hb = f2bf(f);
                ahi[rg][ks][j] = (short)hb;
                alo[rg][ks][j] = (short)f2bf(f - bf2f(hb));
            }
        }
    }

    f32x4 acc[2][8];
#pragma unroll
    for (int rg = 0; rg < 2; ++rg)
#pragma unroll
        for (int c = 0; c < 8; ++c) acc[rg][c] = (f32x4){0.f, 0.f, 0.f, 0.f};

    const bf16x8* whiv = (const bf16x8*)whi;
    const bf16x8* wlov = (const bf16x8*)wlo;

#pragma unroll
    for (int ks = 0; ks < NKS; ++ks) {
#pragma unroll
        for (int c = 0; c < 8; ++c) {
            bf16x8 b = whiv[(size_t)(ks * 8 + c) * 64 + l];
#pragma unroll
            for (int rg = 0; rg < 2; ++rg) {
                acc[rg][c] = __builtin_amdgcn_mfma_f32_16x16x32_bf16(ahi[rg][ks], b, acc[rg][c], 0, 0, 0);
                acc[rg][c] = __builtin_amdgcn_mfma_f32_16x16x32_bf16(alo[rg][ks], b, acc[rg][c], 0, 0, 0);
            }
        }
    }
#pragma unroll
    for (int ks = 0; ks < NKS; ++ks) {
#pragma unroll
        for (int c = 0; c < 8; ++c) {
            bf16x8 b = wlov[(size_t)(ks * 8 + c) * 64 + l];
#pragma unroll
            for (int rg = 0; rg < 2; ++rg)
                acc[rg][c] = __builtin_amdgcn_mfma_f32_16x16x32_bf16(ahi[rg][ks], b, acc[rg][c], 0, 0, 0);
        }
    }

#pragma unroll
    for (int rg = 0; rg < 2; ++rg) {
        float dv[4];
#pragma unroll
        for (int i = 0; i < 4; ++i) {
            int rr = row0 + rg * 16 + q * 4 + i;
            dv[i] = (rr < N) ? dinv[rr] : 0.f;
        }
#pragma unroll
        for (int c = 0; c < 8; ++c) {
#pragma unroll
            for (int i = 0; i < 4; ++i) {
                int rr = row0 + rg * 16 + q * 4 + i;
                if (rr < N) g[(size_t)rr * HID + c * 16 + r] = f2bf(acc[rg][c][i] * dv[i]);
            }
        }
    }
}

// g = dinv[row] * (A @ W) with A PRE-SPLIT (ahi+alo bf16, already relu'd). Layers 2,3.
// 32 rows per wave, no conversion VALU, no launch_bounds cap.
template<int K>
__global__ void k_gemm_pre(const u16* __restrict__ ain_h,
                           const u16* __restrict__ ain_l,
                           const u16* __restrict__ whi,
                           const u16* __restrict__ wlo,
                           const float* __restrict__ dinv,
                           u16* __restrict__ g, int N) {
    constexpr int NKS = K / 32;
    const int w = threadIdx.x >> 6;
    const int l = threadIdx.x & 63;
    const int row0 = blockIdx.x * 128 + w * 32;
    const int r = l & 15;
    const int q = l >> 4;

    bf16x8 ahi[2][NKS], alo[2][NKS];
#pragma unroll
    for (int rg = 0; rg < 2; ++rg) {
        int arow = row0 + rg * 16 + r;
        if (arow > N - 1) arow = N - 1;
        const u16* aph = ain_h + (size_t)arow * K + q * 8;
        const u16* apl = ain_l + (size_t)arow * K + q * 8;
#pragma unroll
        for (int ks = 0; ks < NKS; ++ks) {
            ahi[rg][ks] = *(const bf16x8*)(aph + ks * 32);
            alo[rg][ks] = *(const bf16x8*)(apl + ks * 32);
        }
    }

    f32x4 acc[2][8];
#pragma unroll
    for (int rg = 0; rg < 2; ++rg)
#pragma unroll
        for (int c = 0; c < 8; ++c) acc[rg][c] = (f32x4){0.f, 0.f, 0.f, 0.f};

    const bf16x8* whiv = (const bf16x8*)whi;
    const bf16x8* wlov = (const bf16x8*)wlo;

#pragma unroll
    for (int ks = 0; ks < NKS; ++ks) {
#pragma unroll
        for (int c = 0; c < 8; ++c) {
            bf16x8 b = whiv[(size_t)(ks * 8 + c) * 64 + l];
#pragma unroll
            for (int rg = 0; rg < 2; ++rg) {
                acc[rg][c] = __builtin_amdgcn_mfma_f32_16x16x32_bf16(ahi[rg][ks], b, acc[rg][c], 0, 0, 0);
                acc[rg][c] = __builtin_amdgcn_mfma_f32_16x16x32_bf16(alo[rg][ks], b, acc[rg][c], 0, 0, 0);
            }
        }
    }
#pragma unroll
    for (int ks = 0; ks < NKS; ++ks) {
#pragma unroll
        for (int c = 0; c < 8; ++c) {
            bf16x8 b = wlov[(size_t)(ks * 8 + c) * 64 + l];
#pragma unroll
            for (int rg = 0; rg < 2; ++rg)
                acc[rg][c] = __builtin_amdgcn_mfma_f32_16x16x32_bf16(ahi[rg][ks], b, acc[rg][c], 0, 0, 0);
        }
    }

#pragma unroll
    for (int rg = 0; rg < 2; ++rg) {
        float dv[4];
#pragma unroll
        for (int i = 0; i < 4; ++i) {
            int rr = row0 + rg * 16 + q * 4 + i;
            dv[i] = (rr < N) ? dinv[rr] : 0.f;
        }
#pragma unroll
        for (int c = 0; c < 8; ++c) {
#pragma unroll
            for (int i = 0; i < 4; ++i) {
                int rr = row0 + rg * 16 + q * 4 + i;
                if (rr < N) g[(size_t)rr * HID + c * 16 + r] = f2bf(acc[rg][c][i] * dv[i]);
            }
        }
    }
}

// o[v] = b + dinv[v] * (g[v] + sum g[s]); epilogue writes relu(o) as hi/lo bf16.
// One wave64 per node, 4 streams x 16 lanes x uint4, 2-deep unroll.
#define BFACC(a, p)                                   \
    a[0] += __uint_as_float((p).x << 16);             \
    a[1] += __uint_as_float((p).x & 0xffff0000u);     \
    a[2] += __uint_as_float((p).y << 16);             \
    a[3] += __uint_as_float((p).y & 0xffff0000u);     \
    a[4] += __uint_as_float((p).z << 16);             \
    a[5] += __uint_as_float((p).z & 0xffff0000u);     \
    a[6] += __uint_as_float((p).w << 16);             \
    a[7] += __uint_as_float((p).w & 0xffff0000u);

__global__ __launch_bounds__(256) void k_aggr(const int* __restrict__ rowptr,
                                              const int* __restrict__ sorted,
                                              const u16* __restrict__ g,
                                              const float* __restrict__ dinv,
                                              const float* __restrict__ b,
                                              u16* __restrict__ ahi, u16* __restrict__ alo,
                                              int N) {
    int wid = threadIdx.x >> 6;
    int lane = threadIdx.x & 63;
    int v = blockIdx.x * 4 + wid;
    if (v >= N) return;
    int qq = lane >> 4;              // edge stream 0..3
    int r = lane & 15;
    int cb = r * 16;                 // byte offset of this lane's 8 columns

    const char* gb = (const char*)g;

    float a0[8], a1[8];
#pragma unroll
    for (int i = 0; i < 8; ++i) { a0[i] = 0.f; a1[i] = 0.f; }

    int beg = rowptr[v], end = rowptr[v + 1];
    int j = beg + qq;
    for (; j + 4 < end; j += 8) {
        int o0 = sorted[j];
        int o1 = sorted[j + 4];
        uint4 p0 = *(const uint4*)(gb + o0 + cb);
        uint4 p1 = *(const uint4*)(gb + o1 + cb);
        BFACC(a0, p0);
        BFACC(a1, p1);
    }
    for (; j < end; j += 4) {
        int o0 = sorted[j];
        uint4 p0 = *(const uint4*)(gb + o0 + cb);
        BFACC(a0, p0);
    }

#pragma unroll
    for (int i = 0; i < 8; ++i) {
        float t = a0[i] + a1[i];
        t += __shfl_xor(t, 16);
        t += __shfl_xor(t, 32);
        a0[i] = t;
    }

    if (qq == 0) {
        uint4 sv = *(const uint4*)(gb + ((size_t)v << 8) + cb);
        float se[8];
        se[0] = __uint_as_float(sv.x << 16); se[1] = __uint_as_float(sv.x & 0xffff0000u);
        se[2] = __uint_as_float(sv.y << 16); se[3] = __uint_as_float(sv.y & 0xffff0000u);
        se[4] = __uint_as_float(sv.z << 16); se[5] = __uint_as_float(sv.z & 0xffff0000u);
        se[6] = __uint_as_float(sv.w << 16); se[7] = __uint_as_float(sv.w & 0xffff0000u);
        float dv = dinv[v];
        int c8 = r * 8;
        float4 bv0 = *(const float4*)&b[c8];
        float4 bv1 = *(const float4*)&b[c8 + 4];
        float bb[8] = {bv0.x, bv0.y, bv0.z, bv0.w, bv1.x, bv1.y, bv1.z, bv1.w};
        unsigned H[4], L[4];
#pragma unroll
        for (int p = 0; p < 4; ++p) {
            u16 h2[2], l2[2];
#pragma unroll
            for (int e = 0; e < 2; ++e) {
                int i = p * 2 + e;
                float f = fmaxf(bb[i] + dv * (a0[i] + se[i]), 0.f);  // relu fused
                u16 hb = f2bf(f);
                h2[e] = hb;
                l2[e] = f2bf(f - bf2f(hb));
            }
            H[p] = (unsigned)h2[0] | ((unsigned)h2[1] << 16);
            L[p] = (unsigned)l2[0] | ((unsigned)l2[1] << 16);
        }
        *(uint4*)&ahi[(size_t)v * HID + c8] = make_uint4(H[0], H[1], H[2], H[3]);
        *(uint4*)&alo[(size_t)v * HID + c8] = make_uint4(L[0], L[1], L[2], L[3]);
    }
}

// mean-pool over hi+lo (values already relu'd) + classifier
__global__ __launch_bounds__(256) void k_poolfinal(const u16* __restrict__ ahi,
                                                   const u16* __restrict__ alo,
                                                   const int* __restrict__ gstart,
                                                   const float* __restrict__ Wl,
                                                   const float* __restrict__ bl,
                                                   float* __restrict__ out) {
    __shared__ float part[4][HID];
    __shared__ float pool[HID];
    int g = blockIdx.x;
    int t = threadIdx.x;
    int cp = t & 63;                  // column pair
    int grp = t >> 6;                 // 0..3 node strides
    int beg = gstart[g], end = gstart[g + 1];

    float s0 = 0.f, s1 = 0.f;
    for (int i = beg + grp; i < end; i += 4) {
        unsigned h = *(const unsigned*)&ahi[(size_t)i * HID + cp * 2];
        unsigned l = *(const unsigned*)&alo[(size_t)i * HID + cp * 2];
        s0 += __uint_as_float(h << 16) + __uint_as_float(l << 16);
        s1 += __uint_as_float(h & 0xffff0000u) + __uint_as_float(l & 0xffff0000u);
    }
    part[grp][cp * 2] = s0;
    part[grp][cp * 2 + 1] = s1;
    __syncthreads();
    if (t < HID) {
        float tot = part[0][t] + part[1][t] + part[2][t] + part[3][t];
        float c = fmaxf((float)(end - beg), 1.0f);
        pool[t] = tot / c;
    }
    __syncthreads();
    if (t < NOUT) {
        float a = bl[t];
        for (int k = 0; k < HID; ++k) a += pool[k] * Wl[k * NOUT + t];
        out[g * NOUT + t] = a;
    }
}

__global__ void k_probe(float* __restrict__ out, int n, float val) {
    int i = blockIdx.x * 256 + threadIdx.x;
    if (i < n) out[i] = val;
}

extern "C" void kernel_launch(void* const* d_in, const int* in_sizes, int n_in,
                              void* d_out, int out_size, void* d_ws, size_t ws_size,
                              hipStream_t stream) {
    const float* x    = (const float*)d_in[0];
    const int* ei     = (const int*)d_in[1];     // int64 ref -> int32 device
    const int* batch  = (const int*)d_in[2];
    const float* W1 = (const float*)d_in[3];
    const float* b1 = (const float*)d_in[4];
    const float* W2 = (const float*)d_in[5];
    const float* b2 = (const float*)d_in[6];
    const float* W3 = (const float*)d_in[7];
    const float* b3 = (const float*)d_in[8];
    const float* Wl = (const float*)d_in[9];
    const float* bl = (const float*)d_in[10];
    float* out = (float*)d_out;

    const int N = in_sizes[0] / 64;   // 100000
    const int E = in_sizes[1] / 2;    // 1600000

    // workspace layout (bytes)
    char* ws = (char*)d_ws;
    const size_t off_dinv   = 0;                        // N*4
    const size_t off_counts = 400000;                   // N*4
    const size_t off_rowptr = 800000;                   // (N+1)*4
    const size_t off_rank   = 1200128;                  // E*4
    const size_t off_bsum   = 7600128;                  // 512*4
    const size_t off_gstart = 7602176;                  // (NG+1)*4
    const size_t off_sorted = 7606400;                  // E*4
    const size_t off_g      = 14006400;                 // N*HID*2
    const size_t off_ahi    = 39606400;                 // N*HID*2
    const size_t off_alo    = 65206400;                 // N*HID*2
    const size_t off_wf1h   = 90806400;                 // 64*128*2
    const size_t off_wf1l   = 90822784;
    const size_t off_wf2h   = 90839168;                 // 128*128*2
    const size_t off_wf2l   = 90871936;
    const size_t off_wf3h   = 90904704;
    const size_t off_wf3l   = 90937472;
    const size_t need       = 90970240;                 // ~91.0 MB (known to fit)

    if (ws_size < need) {
        float enc = (float)(ws_size >> 20);
        k_probe<<<(out_size + 255) / 256, 256, 0, stream>>>(out, out_size, enc);
        return;
    }

    float* dinv  = (float*)(ws + off_dinv);
    int* counts  = (int*)(ws + off_counts);
    int* rowptr  = (int*)(ws + off_rowptr);
    int* rank    = (int*)(ws + off_rank);
    int* bsum    = (int*)(ws + off_bsum);
    int* gstart  = (int*)(ws + off_gstart);
    int* sorted  = (int*)(ws + off_sorted);
    u16* g       = (u16*)(ws + off_g);
    u16* ahi     = (u16*)(ws + off_ahi);
    u16* alo     = (u16*)(ws + off_alo);
    u16* wf1h = (u16*)(ws + off_wf1h);  u16* wf1l = (u16*)(ws + off_wf1l);
    u16* wf2h = (u16*)(ws + off_wf2h);  u16* wf2l = (u16*)(ws + off_wf2l);
    u16* wf3h = (u16*)(ws + off_wf3h);  u16* wf3l = (u16*)(ws + off_wf3l);

    dim3 blk(256);
    const int gN = (N + 255) / 256;
    const int gE = (E + 255) / 256;
    const int nScanBlk = (N + SCAN_B - 1) / SCAN_B;
    const int mfmaGrid = (N + 127) / 128;             // 32 rows/wave, 128 rows/block
    const int aggrGrid = (N + 3) / 4;                 // one wave64 per node

    // ---- fused setup + CSR build ----
    k_setup<<<gN, blk, 0, stream>>>(batch, gstart, counts, W1, W2, W3,
                                    wf1h, wf1l, wf2h, wf2l, wf3h, wf3l, N);
    k_count_rank<<<gE, blk, 0, stream>>>(ei, counts, rank, E);
    k_scan1<<<nScanBlk, SCAN_B, 0, stream>>>(counts, rowptr, bsum, dinv, N);
    k_scan2<<<1, 512, 0, stream>>>(bsum, nScanBlk);
    k_scan3<<<nScanBlk, SCAN_B, 0, stream>>>(rowptr, bsum, N, E);
    k_scatter<<<gE, blk, 0, stream>>>(ei, rank, rowptr, sorted, E);

    // ---- 3 GCN layers ----
    k_gemm_f32<64><<<mfmaGrid, blk, 0, stream>>>(x, wf1h, wf1l, dinv, g, N);
    k_aggr<<<aggrGrid, blk, 0, stream>>>(rowptr, sorted, g, dinv, b1, ahi, alo, N);
    k_gemm_pre<128><<<mfmaGrid, blk, 0, stream>>>(ahi, alo, wf2h, wf2l, dinv, g, N);
    k_aggr<<<aggrGrid, blk, 0, stream>>>(rowptr, sorted, g, dinv, b2, ahi, alo, N);
    k_gemm_pre<128><<<mfmaGrid, blk, 0, stream>>>(ahi, alo, wf3h, wf3l, dinv, g, N);
    k_aggr<<<aggrGrid, blk, 0, stream>>>(rowptr, sorted, g, dinv, b3, ahi, alo, N);

    // ---- mean pool (hi+lo) + classifier ----
    k_poolfinal<<<NG, blk, 0, stream>>>(ahi, alo, gstart, Wl, bl, out);
}

// Round 13
// 410.897 us; speedup vs baseline: 1.2481x; 1.0077x over previous
//
#include <hip/hip_runtime.h>
#include <math.h>

#define HID 128
#define NOUT 10
#define NG 1000
#define SCAN_B 256

typedef unsigned short u16;
typedef __attribute__((ext_vector_type(8))) short bf16x8;
typedef __attribute__((ext_vector_type(4))) float f32x4;

__device__ inline u16 f2bf(float f) {
    unsigned x = __float_as_uint(f);
    return (u16)((x + 0x7FFF + ((x >> 16) & 1)) >> 16);  // RNE
}
__device__ inline float bf2f(u16 b) { return __uint_as_float(((unsigned)b) << 16); }

// counts[d]++ AND capture per-edge rank (position within its dst bucket)
__global__ void k_count_rank(const int* __restrict__ ei, int* __restrict__ counts,
                             int* __restrict__ rank, int E) {
    int e = blockIdx.x * 256 + threadIdx.x;
    if (e < E) rank[e] = atomicAdd(&counts[ei[(size_t)E + e]], 1);
}

// fused setup: zero counts + graph boundaries + weight hi/lo fragment packing
__global__ void k_setup(const int* __restrict__ batch, int* __restrict__ gstart,
                        int* __restrict__ counts,
                        const float* __restrict__ W1, const float* __restrict__ W2,
                        const float* __restrict__ W3,
                        u16* __restrict__ w1h, u16* __restrict__ w1l,
                        u16* __restrict__ w2h, u16* __restrict__ w2l,
                        u16* __restrict__ w3h, u16* __restrict__ w3l, int N) {
    int i = blockIdx.x * 256 + threadIdx.x;
    if (i < N) {
        counts[i] = 0;
        int cur = batch[i];
        if (i == 0) {
            for (int g = 0; g <= cur; ++g) gstart[g] = 0;
        } else {
            int prev = batch[i - 1];
            for (int g = prev + 1; g <= cur; ++g) gstart[g] = i;
        }
        if (i == N - 1) {
            for (int g = cur + 1; g <= NG; ++g) gstart[g] = N;
        }
    }
    if (i < 320 * HID) {
        const float* W; u16 *wh, *wl; int base;
        if (i < 64 * HID)       { W = W1; wh = w1h; wl = w1l; base = i; }
        else if (i < 192 * HID) { W = W2; wh = w2h; wl = w2l; base = i - 64 * HID; }
        else                    { W = W3; wh = w3h; wl = w3l; base = i - 192 * HID; }
        int k = base >> 7;
        int col = base & 127;
        float v = W[base];
        u16 hb = f2bf(v);
        u16 lb = f2bf(v - bf2f(hb));
        int ks = k >> 5;
        int kq = (k >> 3) & 3;
        int j = k & 7;
        int c = col >> 4;
        int r = col & 15;
        int lane = kq * 16 + r;
        size_t pos = ((size_t)(ks * 8 + c) * 64 + lane) * 8 + j;
        wh[pos] = hb;
        wl[pos] = lb;
    }
}

// block-local exclusive scan of counts -> rowptr; block sums -> bsum; also dinv
__global__ __launch_bounds__(SCAN_B) void k_scan1(const int* __restrict__ counts,
                                                  int* __restrict__ rowptr,
                                                  int* __restrict__ bsum,
                                                  float* __restrict__ dinv, int N) {
    __shared__ int s[SCAN_B];
    int t = threadIdx.x;
    int i = blockIdx.x * SCAN_B + t;
    int v = (i < N) ? counts[i] : 0;
    if (i < N) dinv[i] = rsqrtf((float)(v + 1));  // +1 self-loop
    s[t] = v;
    __syncthreads();
    for (int off = 1; off < SCAN_B; off <<= 1) {
        int u = (t >= off) ? s[t - off] : 0;
        __syncthreads();
        s[t] += u;
        __syncthreads();
    }
    if (i < N) rowptr[i] = s[t] - v;
    if (t == SCAN_B - 1) bsum[blockIdx.x] = s[t];
}

__global__ __launch_bounds__(512) void k_scan2(int* __restrict__ bsum, int nb) {
    __shared__ int s[512];
    int t = threadIdx.x;
    int v = (t < nb) ? bsum[t] : 0;
    s[t] = v;
    __syncthreads();
    for (int off = 1; off < 512; off <<= 1) {
        int u = (t >= off) ? s[t - off] : 0;
        __syncthreads();
        s[t] += u;
        __syncthreads();
    }
    if (t < nb) bsum[t] = s[t] - v;
}

__global__ void k_scan3(int* __restrict__ rowptr, const int* __restrict__ bsum, int N, int E) {
    int i = blockIdx.x * SCAN_B + threadIdx.x;
    if (i < N) rowptr[i] += bsum[blockIdx.x];
    if (i == 0) rowptr[N] = E;
}

// sorted[rowptr[d] + rank[e]] = src byte-offset (src*256)
__global__ void k_scatter(const int* __restrict__ ei, const int* __restrict__ rank,
                          const int* __restrict__ rowptr, int* __restrict__ sorted, int E) {
    int e = blockIdx.x * 256 + threadIdx.x;
    if (e >= E) return;
    int s = ei[e];
    int d = ei[(size_t)E + e];
    sorted[rowptr[d] + rank[e]] = s << 8;   // byte offset into g (HID*2 = 256 B rows)
}

// g(bf16)[N][128] = dinv[row] * (in_fp32[N][K] @ W) via MFMA hi/lo split. Layer 1.
// 32 rows per wave: 2 row-groups share every B-fragment load. No launch_bounds cap.
template<int K>
__global__ void k_gemm_f32(const float* __restrict__ in,
                           const u16* __restrict__ whi,
                           const u16* __restrict__ wlo,
                           const float* __restrict__ dinv,
                           u16* __restrict__ g, int N) {
    constexpr int NKS = K / 32;
    const int w = threadIdx.x >> 6;
    const int l = threadIdx.x & 63;
    const int row0 = blockIdx.x * 128 + w * 32;
    const int r = l & 15;
    const int q = l >> 4;

    bf16x8 ahi[2][NKS], alo[2][NKS];
#pragma unroll
    for (int rg = 0; rg < 2; ++rg) {
        int arow = row0 + rg * 16 + r;
        if (arow > N - 1) arow = N - 1;
        const float* ap = in + (size_t)arow * K + q * 8;
#pragma unroll
        for (int ks = 0; ks < NKS; ++ks) {
            float4 v0 = *(const float4*)(ap + ks * 32);
            float4 v1 = *(const float4*)(ap + ks * 32 + 4);
            float va[8] = {v0.x, v0.y, v0.z, v0.w, v1.x, v1.y, v1.z, v1.w};
#pragma unroll
            for (int j = 0; j < 8; ++j) {
                float f = va[j];
                u16 hb = f2bf(f);
                ahi[rg][ks][j] = (short)hb;
                alo[rg][ks][j] = (short)f2bf(f - bf2f(hb));
            }
        }
    }

    f32x4 acc[2][8];
#pragma unroll
    for (int rg = 0; rg < 2; ++rg)
#pragma unroll
        for (int c = 0; c < 8; ++c) acc[rg][c] = (f32x4){0.f, 0.f, 0.f, 0.f};

    const bf16x8* whiv = (const bf16x8*)whi;
    const bf16x8* wlov = (const bf16x8*)wlo;

#pragma unroll
    for (int ks = 0; ks < NKS; ++ks) {
#pragma unroll
        for (int c = 0; c < 8; ++c) {
            bf16x8 b = whiv[(size_t)(ks * 8 + c) * 64 + l];
#pragma unroll
            for (int rg = 0; rg < 2; ++rg) {
                acc[rg][c] = __builtin_amdgcn_mfma_f32_16x16x32_bf16(ahi[rg][ks], b, acc[rg][c], 0, 0, 0);
                acc[rg][c] = __builtin_amdgcn_mfma_f32_16x16x32_bf16(alo[rg][ks], b, acc[rg][c], 0, 0, 0);
            }
        }
    }
#pragma unroll
    for (int ks = 0; ks < NKS; ++ks) {
#pragma unroll
        for (int c = 0; c < 8; ++c) {
            bf16x8 b = wlov[(size_t)(ks * 8 + c) * 64 + l];
#pragma unroll
            for (int rg = 0; rg < 2; ++rg)
                acc[rg][c] = __builtin_amdgcn_mfma_f32_16x16x32_bf16(ahi[rg][ks], b, acc[rg][c], 0, 0, 0);
        }
    }

#pragma unroll
    for (int rg = 0; rg < 2; ++rg) {
        float dv[4];
#pragma unroll
        for (int i = 0; i < 4; ++i) {
            int rr = row0 + rg * 16 + q * 4 + i;
            dv[i] = (rr < N) ? dinv[rr] : 0.f;
        }
#pragma unroll
        for (int c = 0; c < 8; ++c) {
#pragma unroll
            for (int i = 0; i < 4; ++i) {
                int rr = row0 + rg * 16 + q * 4 + i;
                if (rr < N) g[(size_t)rr * HID + c * 16 + r] = f2bf(acc[rg][c][i] * dv[i]);
            }
        }
    }
}

// g = dinv[row] * (A @ W) with A PRE-SPLIT (ahi+alo bf16, already relu'd). Layers 2,3.
template<int K>
__global__ void k_gemm_pre(const u16* __restrict__ ain_h,
                           const u16* __restrict__ ain_l,
                           const u16* __restrict__ whi,
                           const u16* __restrict__ wlo,
                           const float* __restrict__ dinv,
                           u16* __restrict__ g, int N) {
    constexpr int NKS = K / 32;
    const int w = threadIdx.x >> 6;
    const int l = threadIdx.x & 63;
    const int row0 = blockIdx.x * 128 + w * 32;
    const int r = l & 15;
    const int q = l >> 4;

    bf16x8 ahi[2][NKS], alo[2][NKS];
#pragma unroll
    for (int rg = 0; rg < 2; ++rg) {
        int arow = row0 + rg * 16 + r;
        if (arow > N - 1) arow = N - 1;
        const u16* aph = ain_h + (size_t)arow * K + q * 8;
        const u16* apl = ain_l + (size_t)arow * K + q * 8;
#pragma unroll
        for (int ks = 0; ks < NKS; ++ks) {
            ahi[rg][ks] = *(const bf16x8*)(aph + ks * 32);
            alo[rg][ks] = *(const bf16x8*)(apl + ks * 32);
        }
    }

    f32x4 acc[2][8];
#pragma unroll
    for (int rg = 0; rg < 2; ++rg)
#pragma unroll
        for (int c = 0; c < 8; ++c) acc[rg][c] = (f32x4){0.f, 0.f, 0.f, 0.f};

    const bf16x8* whiv = (const bf16x8*)whi;
    const bf16x8* wlov = (const bf16x8*)wlo;

#pragma unroll
    for (int ks = 0; ks < NKS; ++ks) {
#pragma unroll
        for (int c = 0; c < 8; ++c) {
            bf16x8 b = whiv[(size_t)(ks * 8 + c) * 64 + l];
#pragma unroll
            for (int rg = 0; rg < 2; ++rg) {
                acc[rg][c] = __builtin_amdgcn_mfma_f32_16x16x32_bf16(ahi[rg][ks], b, acc[rg][c], 0, 0, 0);
                acc[rg][c] = __builtin_amdgcn_mfma_f32_16x16x32_bf16(alo[rg][ks], b, acc[rg][c], 0, 0, 0);
            }
        }
    }
#pragma unroll
    for (int ks = 0; ks < NKS; ++ks) {
#pragma unroll
        for (int c = 0; c < 8; ++c) {
            bf16x8 b = wlov[(size_t)(ks * 8 + c) * 64 + l];
#pragma unroll
            for (int rg = 0; rg < 2; ++rg)
                acc[rg][c] = __builtin_amdgcn_mfma_f32_16x16x32_bf16(ahi[rg][ks], b, acc[rg][c], 0, 0, 0);
        }
    }

#pragma unroll
    for (int rg = 0; rg < 2; ++rg) {
        float dv[4];
#pragma unroll
        for (int i = 0; i < 4; ++i) {
            int rr = row0 + rg * 16 + q * 4 + i;
            dv[i] = (rr < N) ? dinv[rr] : 0.f;
        }
#pragma unroll
        for (int c = 0; c < 8; ++c) {
#pragma unroll
            for (int i = 0; i < 4; ++i) {
                int rr = row0 + rg * 16 + q * 4 + i;
                if (rr < N) g[(size_t)rr * HID + c * 16 + r] = f2bf(acc[rg][c][i] * dv[i]);
            }
        }
    }
}

// o[v] = b + dinv[v] * (g[v] + sum g[s]); writes relu(o) as hi/lo bf16.
// Loop: one wave64/node, 4 streams x 16 lanes x uint4, 2-deep (round-9 shape).
// Reduce-scatter: staged shfl_xor leaves each lane owning 2 columns' totals,
// then the epilogue runs on ALL 64 lanes (2 elems/lane) instead of 16.
#define BFACC(a, p)                                   \
    a[0] += __uint_as_float((p).x << 16);             \
    a[1] += __uint_as_float((p).x & 0xffff0000u);     \
    a[2] += __uint_as_float((p).y << 16);             \
    a[3] += __uint_as_float((p).y & 0xffff0000u);     \
    a[4] += __uint_as_float((p).z << 16);             \
    a[5] += __uint_as_float((p).z & 0xffff0000u);     \
    a[6] += __uint_as_float((p).w << 16);             \
    a[7] += __uint_as_float((p).w & 0xffff0000u);

__global__ __launch_bounds__(256) void k_aggr(const int* __restrict__ rowptr,
                                              const int* __restrict__ sorted,
                                              const u16* __restrict__ g,
                                              const float* __restrict__ dinv,
                                              const float* __restrict__ b,
                                              u16* __restrict__ ahi, u16* __restrict__ alo,
                                              int N) {
    int wid = threadIdx.x >> 6;
    int lane = threadIdx.x & 63;
    int v = blockIdx.x * 4 + wid;
    if (v >= N) return;
    int qq = lane >> 4;              // edge stream 0..3
    int r = lane & 15;
    int cb = r * 16;                 // byte offset of this lane's 8 columns (loop)

    const char* gb = (const char*)g;

    float a0[8], a1[8];
#pragma unroll
    for (int i = 0; i < 8; ++i) { a0[i] = 0.f; a1[i] = 0.f; }

    int beg = rowptr[v], end = rowptr[v + 1];
    int j = beg + qq;
    for (; j + 4 < end; j += 8) {
        int o0 = sorted[j];
        int o1 = sorted[j + 4];
        uint4 p0 = *(const uint4*)(gb + o0 + cb);
        uint4 p1 = *(const uint4*)(gb + o1 + cb);
        BFACC(a0, p0);
        BFACC(a1, p1);
    }
    for (; j < end; j += 4) {
        int o0 = sorted[j];
        uint4 p0 = *(const uint4*)(gb + o0 + cb);
        BFACC(a0, p0);
    }
#pragma unroll
    for (int i = 0; i < 8; ++i) a0[i] += a1[i];

    // reduce-scatter stage 1 (lane ^ 16): keep 4 elems per lane
    bool h1 = (lane & 16) != 0;
    float s1[4];
#pragma unroll
    for (int i = 0; i < 4; ++i) {
        float keep = h1 ? a0[i + 4] : a0[i];
        float send = h1 ? a0[i] : a0[i + 4];
        s1[i] = keep + __shfl_xor(send, 16);
    }
    // stage 2 (lane ^ 32): keep 2 elems per lane
    bool h2 = (lane & 32) != 0;
    float s2[2];
#pragma unroll
    for (int i = 0; i < 2; ++i) {
        float keep = h2 ? s1[i + 2] : s1[i];
        float send = h2 ? s1[i] : s1[i + 2];
        s2[i] = keep + __shfl_xor(send, 32);
    }
    int base2 = (h1 ? 4 : 0) + (h2 ? 2 : 0);
    int c0 = r * 8 + base2;          // this lane's first column
    int byte0 = c0 * 2;

    // all-lane epilogue: 2 elems/lane
    unsigned sv = *(const unsigned*)(gb + ((size_t)v << 8) + byte0);
    float dv = dinv[v];
    float2 bv = *(const float2*)&b[c0];
    float f0 = fmaxf(bv.x + dv * (s2[0] + __uint_as_float(sv << 16)), 0.f);
    float f1 = fmaxf(bv.y + dv * (s2[1] + __uint_as_float(sv & 0xffff0000u)), 0.f);
    u16 hb0 = f2bf(f0), hb1 = f2bf(f1);
    u16 lb0 = f2bf(f0 - bf2f(hb0)), lb1 = f2bf(f1 - bf2f(hb1));
    unsigned H = (unsigned)hb0 | ((unsigned)hb1 << 16);
    unsigned L = (unsigned)lb0 | ((unsigned)lb1 << 16);
    *(unsigned*)&ahi[(size_t)v * HID + c0] = H;
    *(unsigned*)&alo[(size_t)v * HID + c0] = L;
}

// mean-pool over hi+lo (values already relu'd) + classifier
__global__ __launch_bounds__(256) void k_poolfinal(const u16* __restrict__ ahi,
                                                   const u16* __restrict__ alo,
                                                   const int* __restrict__ gstart,
                                                   const float* __restrict__ Wl,
                                                   const float* __restrict__ bl,
                                                   float* __restrict__ out) {
    __shared__ float part[4][HID];
    __shared__ float pool[HID];
    int g = blockIdx.x;
    int t = threadIdx.x;
    int cp = t & 63;                  // column pair
    int grp = t >> 6;                 // 0..3 node strides
    int beg = gstart[g], end = gstart[g + 1];

    float s0 = 0.f, s1 = 0.f;
    for (int i = beg + grp; i < end; i += 4) {
        unsigned h = *(const unsigned*)&ahi[(size_t)i * HID + cp * 2];
        unsigned l = *(const unsigned*)&alo[(size_t)i * HID + cp * 2];
        s0 += __uint_as_float(h << 16) + __uint_as_float(l << 16);
        s1 += __uint_as_float(h & 0xffff0000u) + __uint_as_float(l & 0xffff0000u);
    }
    part[grp][cp * 2] = s0;
    part[grp][cp * 2 + 1] = s1;
    __syncthreads();
    if (t < HID) {
        float tot = part[0][t] + part[1][t] + part[2][t] + part[3][t];
        float c = fmaxf((float)(end - beg), 1.0f);
        pool[t] = tot / c;
    }
    __syncthreads();
    if (t < NOUT) {
        float a = bl[t];
        for (int k = 0; k < HID; ++k) a += pool[k] * Wl[k * NOUT + t];
        out[g * NOUT + t] = a;
    }
}

__global__ void k_probe(float* __restrict__ out, int n, float val) {
    int i = blockIdx.x * 256 + threadIdx.x;
    if (i < n) out[i] = val;
}

extern "C" void kernel_launch(void* const* d_in, const int* in_sizes, int n_in,
                              void* d_out, int out_size, void* d_ws, size_t ws_size,
                              hipStream_t stream) {
    const float* x    = (const float*)d_in[0];
    const int* ei     = (const int*)d_in[1];     // int64 ref -> int32 device
    const int* batch  = (const int*)d_in[2];
    const float* W1 = (const float*)d_in[3];
    const float* b1 = (const float*)d_in[4];
    const float* W2 = (const float*)d_in[5];
    const float* b2 = (const float*)d_in[6];
    const float* W3 = (const float*)d_in[7];
    const float* b3 = (const float*)d_in[8];
    const float* Wl = (const float*)d_in[9];
    const float* bl = (const float*)d_in[10];
    float* out = (float*)d_out;

    const int N = in_sizes[0] / 64;   // 100000
    const int E = in_sizes[1] / 2;    // 1600000

    // workspace layout (bytes)
    char* ws = (char*)d_ws;
    const size_t off_dinv   = 0;                        // N*4
    const size_t off_counts = 400000;                   // N*4
    const size_t off_rowptr = 800000;                   // (N+1)*4
    const size_t off_rank   = 1200128;                  // E*4
    const size_t off_bsum   = 7600128;                  // 512*4
    const size_t off_gstart = 7602176;                  // (NG+1)*4
    const size_t off_sorted = 7606400;                  // E*4
    const size_t off_g      = 14006400;                 // N*HID*2
    const size_t off_ahi    = 39606400;                 // N*HID*2
    const size_t off_alo    = 65206400;                 // N*HID*2
    const size_t off_wf1h   = 90806400;                 // 64*128*2
    const size_t off_wf1l   = 90822784;
    const size_t off_wf2h   = 90839168;                 // 128*128*2
    const size_t off_wf2l   = 90871936;
    const size_t off_wf3h   = 90904704;
    const size_t off_wf3l   = 90937472;
    const size_t need       = 90970240;                 // ~91.0 MB (known to fit)

    if (ws_size < need) {
        float enc = (float)(ws_size >> 20);
        k_probe<<<(out_size + 255) / 256, 256, 0, stream>>>(out, out_size, enc);
        return;
    }

    float* dinv  = (float*)(ws + off_dinv);
    int* counts  = (int*)(ws + off_counts);
    int* rowptr  = (int*)(ws + off_rowptr);
    int* rank    = (int*)(ws + off_rank);
    int* bsum    = (int*)(ws + off_bsum);
    int* gstart  = (int*)(ws + off_gstart);
    int* sorted  = (int*)(ws + off_sorted);
    u16* g       = (u16*)(ws + off_g);
    u16* ahi     = (u16*)(ws + off_ahi);
    u16* alo     = (u16*)(ws + off_alo);
    u16* wf1h = (u16*)(ws + off_wf1h);  u16* wf1l = (u16*)(ws + off_wf1l);
    u16* wf2h = (u16*)(ws + off_wf2h);  u16* wf2l = (u16*)(ws + off_wf2l);
    u16* wf3h = (u16*)(ws + off_wf3h);  u16* wf3l = (u16*)(ws + off_wf3l);

    dim3 blk(256);
    const int gN = (N + 255) / 256;
    const int gE = (E + 255) / 256;
    const int nScanBlk = (N + SCAN_B - 1) / SCAN_B;
    const int mfmaGrid = (N + 127) / 128;             // 32 rows/wave, 128 rows/block
    const int aggrGrid = (N + 3) / 4;                 // one wave64 per node

    // ---- fused setup + CSR build ----
    k_setup<<<gN, blk, 0, stream>>>(batch, gstart, counts, W1, W2, W3,
                                    wf1h, wf1l, wf2h, wf2l, wf3h, wf3l, N);
    k_count_rank<<<gE, blk, 0, stream>>>(ei, counts, rank, E);
    k_scan1<<<nScanBlk, SCAN_B, 0, stream>>>(counts, rowptr, bsum, dinv, N);
    k_scan2<<<1, 512, 0, stream>>>(bsum, nScanBlk);
    k_scan3<<<nScanBlk, SCAN_B, 0, stream>>>(rowptr, bsum, N, E);
    k_scatter<<<gE, blk, 0, stream>>>(ei, rank, rowptr, sorted, E);

    // ---- 3 GCN layers ----
    k_gemm_f32<64><<<mfmaGrid, blk, 0, stream>>>(x, wf1h, wf1l, dinv, g, N);
    k_aggr<<<aggrGrid, blk, 0, stream>>>(rowptr, sorted, g, dinv, b1, ahi, alo, N);
    k_gemm_pre<128><<<mfmaGrid, blk, 0, stream>>>(ahi, alo, wf2h, wf2l, dinv, g, N);
    k_aggr<<<aggrGrid, blk, 0, stream>>>(rowptr, sorted, g, dinv, b2, ahi, alo, N);
    k_gemm_pre<128><<<mfmaGrid, blk, 0, stream>>>(ahi, alo, wf3h, wf3l, dinv, g, N);
    k_aggr<<<aggrGrid, blk, 0, stream>>>(rowptr, sorted, g, dinv, b3, ahi, alo, N);

    // ---- mean pool (hi+lo) + classifier ----
    k_poolfinal<<<NG, blk, 0, stream>>>(ahi, alo, gstart, Wl, bl, out);
}